// Round 1
// baseline (106.889 us; speedup 1.0000x reference)
//
#include <hip/hip_runtime.h>
#include <math.h>

#define BB    16
#define LL    4096
#define TMAX  512
#define DIN   512
#define DHID  256
#define DOUT  3

// ---------------------------------------------------------------------------
// Kernel 1: per-batch exclusive scan of effective durations.
//   d      = max(floor(ds * L/Lmax), 1)
//   d_eff  = (ds > 0) ? d : 0
//   starts = exclusive cumsum of d_eff along t
// ---------------------------------------------------------------------------
__global__ __launch_bounds__(TMAX) void scan_kernel(const int* __restrict__ ds,
                                                    const int* __restrict__ lmax,
                                                    int* __restrict__ starts,
                                                    int* __restrict__ lens) {
    __shared__ int sbuf[TMAX];
    const int b = blockIdx.x;
    const int t = threadIdx.x;
    const float mult = (float)LL / (float)lmax[0];
    const int dsv = ds[b * TMAX + t];
    int d = (int)floorf((float)dsv * mult);
    d = max(d, 1);
    const int deff = (dsv > 0) ? d : 0;
    sbuf[t] = deff;
    __syncthreads();
    // Hillis-Steele inclusive scan (in-place, double barrier per step)
    for (int off = 1; off < TMAX; off <<= 1) {
        int x = (t >= off) ? sbuf[t - off] : 0;
        __syncthreads();
        sbuf[t] += x;
        __syncthreads();
    }
    starts[b * TMAX + t] = sbuf[t] - deff;  // exclusive
    lens[b * TMAX + t]   = deff;
}

__device__ __forceinline__ float f4c(const float4& v, int q) {
    switch (q) {
        case 0:  return v.x;
        case 1:  return v.y;
        case 2:  return v.z;
        default: return v.w;
    }
}

// ---------------------------------------------------------------------------
// Kernel 2: fused segment-mean + MLP.
// One block (512 threads) handles 32 consecutive rows (b, t0..t0+31).
//   Phase 1: aligned rows -> LDS al[32][512]   (lane = column, coalesced)
//   Phase 2: h = relu(al @ W1 + b1), register tile 2 rows x 8 cols / thread
//   Phase 3: out = relu(h @ W2 + b2), in-register + half-wave shfl reduce
// ---------------------------------------------------------------------------
__global__ __launch_bounds__(512) void fused_kernel(
    const float* __restrict__ hs, const float* __restrict__ W1,
    const float* __restrict__ b1, const float* __restrict__ W2,
    const float* __restrict__ b2, const int* __restrict__ starts,
    const int* __restrict__ lens, float* __restrict__ out) {
    __shared__ float al[32][DIN];  // 64 KB

    const int bid = blockIdx.x;
    const int b   = bid >> 4;          // 16 blocks per batch
    const int t0  = (bid & 15) * 32;
    const int tid = threadIdx.x;

    // ---- Phase 1: segment means into LDS (thread owns column `tid`) ----
    const float* hsb = hs + (size_t)b * LL * DIN + tid;
    #pragma unroll 2
    for (int r = 0; r < 32; ++r) {
        const int t   = t0 + r;
        const int len = lens[b * TMAX + t];
        int s = starts[b * TMAX + t];
        int e = min(s + len, LL);
        s = min(s, LL);
        const int n = e - s;
        float a = 0.0f;
        const float* p = hsb + (size_t)s * DIN;
        for (int i = 0; i < n; ++i) { a += *p; p += DIN; }
        const float inv = (len > 0) ? (1.0f / (float)max(n, 1)) : 0.0f;
        al[r][tid] = a * inv;
    }
    __syncthreads();

    // ---- Phase 2: h = relu(al @ W1 + b1), tile = 2 rows x 8 cols ----
    const int rg = tid >> 5;   // 0..15 -> row pair
    const int cg = tid & 31;   // 0..31 -> 8 h-columns
    const int r0 = rg * 2;
    const int j0 = cg * 8;

    float acc[2][8];
    #pragma unroll
    for (int r = 0; r < 2; ++r)
        #pragma unroll
        for (int j = 0; j < 8; ++j) acc[r][j] = 0.0f;

    const float* w1p = W1 + j0;
    for (int kk = 0; kk < DIN; kk += 4) {
        const float4 a0 = *(const float4*)&al[r0][kk];
        const float4 a1 = *(const float4*)&al[r0 + 1][kk];
        float4 w[4][2];
        #pragma unroll
        for (int q = 0; q < 4; ++q) {
            const float* wp = w1p + (size_t)(kk + q) * DHID;
            w[q][0] = *(const float4*)wp;
            w[q][1] = *(const float4*)(wp + 4);
        }
        #pragma unroll
        for (int q = 0; q < 4; ++q) {
            const float av0 = f4c(a0, q);
            const float av1 = f4c(a1, q);
            #pragma unroll
            for (int j = 0; j < 4; ++j) {
                acc[0][j]     = fmaf(av0, f4c(w[q][0], j), acc[0][j]);
                acc[0][j + 4] = fmaf(av0, f4c(w[q][1], j), acc[0][j + 4]);
                acc[1][j]     = fmaf(av1, f4c(w[q][0], j), acc[1][j]);
                acc[1][j + 4] = fmaf(av1, f4c(w[q][1], j), acc[1][j + 4]);
            }
        }
    }

    // ---- Phase 3: out = relu(h @ W2 + b2) ----
    float pr[2][3] = {{0.f, 0.f, 0.f}, {0.f, 0.f, 0.f}};
    #pragma unroll
    for (int jj = 0; jj < 8; ++jj) {
        const int j = j0 + jj;
        const float bb1 = b1[j];
        const float w20 = W2[j * 3 + 0];
        const float w21 = W2[j * 3 + 1];
        const float w22 = W2[j * 3 + 2];
        #pragma unroll
        for (int r = 0; r < 2; ++r) {
            const float h = fmaxf(acc[r][jj] + bb1, 0.0f);
            pr[r][0] = fmaf(h, w20, pr[r][0]);
            pr[r][1] = fmaf(h, w21, pr[r][1]);
            pr[r][2] = fmaf(h, w22, pr[r][2]);
        }
    }
    // reduce the 256 h-columns across the 32 lanes of each half-wave
    #pragma unroll
    for (int m = 16; m >= 1; m >>= 1) {
        #pragma unroll
        for (int r = 0; r < 2; ++r)
            #pragma unroll
            for (int o = 0; o < 3; ++o)
                pr[r][o] += __shfl_xor(pr[r][o], m, 64);
    }
    if (cg == 0) {
        #pragma unroll
        for (int r = 0; r < 2; ++r) {
            const int t = t0 + r0 + r;
            float* op = out + ((size_t)b * TMAX + t) * DOUT;
            #pragma unroll
            for (int o = 0; o < 3; ++o)
                op[o] = fmaxf(pr[r][o] + b2[o], 0.0f);
        }
    }
}

extern "C" void kernel_launch(void* const* d_in, const int* in_sizes, int n_in,
                              void* d_out, int out_size, void* d_ws, size_t ws_size,
                              hipStream_t stream) {
    const float* hs  = (const float*)d_in[0];
    const int*   ds  = (const int*)d_in[1];
    const float* W1  = (const float*)d_in[2];
    const float* b1  = (const float*)d_in[3];
    const float* W2  = (const float*)d_in[4];
    const float* b2  = (const float*)d_in[5];
    const int*   lmx = (const int*)d_in[6];

    int* starts = (int*)d_ws;
    int* lens   = starts + BB * TMAX;

    scan_kernel<<<BB, TMAX, 0, stream>>>(ds, lmx, starts, lens);
    fused_kernel<<<BB * 16, 512, 0, stream>>>(hs, W1, b1, W2, b2, starts, lens,
                                              (float*)d_out);
}

// Round 2
// 74.545 us; speedup vs baseline: 1.4339x; 1.4339x over previous
//
#include <hip/hip_runtime.h>
#include <math.h>

#define BB    16
#define LL    4096
#define TMAX  512
#define DIN   512
#define DHID  256
#define DOUT  3
#define NROW  (BB * TMAX)   // 8192
#define KT    128           // k-tile for GEMM staging

// ---------------------------------------------------------------------------
// ws layout (float units):
//   [0      .. 8191 ]  starts (int)
//   [8192   .. 16383]  lens   (int)
//   [16384  .. 40959]  acc    (NROW*DOUT floats, atomically accumulated)
//   [65536  .. +4M  ]  aligned (NROW*DIN floats, 16B aligned offset)
// ---------------------------------------------------------------------------

__global__ __launch_bounds__(TMAX) void scan_kernel(const int* __restrict__ ds,
                                                    const int* __restrict__ lmax,
                                                    int* __restrict__ starts,
                                                    int* __restrict__ lens) {
    __shared__ int sbuf[TMAX];
    const int b = blockIdx.x;
    const int t = threadIdx.x;
    const float mult = (float)LL / (float)lmax[0];
    const int dsv = ds[b * TMAX + t];
    int d = (int)floorf((float)dsv * mult);
    d = max(d, 1);
    const int deff = (dsv > 0) ? d : 0;
    sbuf[t] = deff;
    __syncthreads();
    for (int off = 1; off < TMAX; off <<= 1) {
        int x = (t >= off) ? sbuf[t - off] : 0;
        __syncthreads();
        sbuf[t] += x;
        __syncthreads();
    }
    starts[b * TMAX + t] = sbuf[t] - deff;
    lens[b * TMAX + t]   = deff;
}

// ---------------------------------------------------------------------------
// One block per output row: segment mean, massively parallel (8192 blocks).
// thread owns 2 columns (float2, 8B/lane coalesced).
// ---------------------------------------------------------------------------
__global__ __launch_bounds__(256) void align_kernel(const float* __restrict__ hs,
                                                    const int* __restrict__ starts,
                                                    const int* __restrict__ lens,
                                                    float* __restrict__ aligned) {
    const int bid = blockIdx.x;          // row id 0..NROW-1
    const int b   = bid >> 9;            // /TMAX
    const int tid = threadIdx.x;

    const int len = lens[bid];
    int s = starts[bid];
    int e = min(s + len, LL);
    s = min(s, LL);
    const int n = e - s;

    const float* p = hs + ((size_t)b * LL + (size_t)s) * DIN + tid * 2;
    float a0 = 0.0f, a1 = 0.0f;
    for (int i = 0; i < n; ++i) {
        const float2 v = *(const float2*)p;
        a0 += v.x;
        a1 += v.y;
        p += DIN;
    }
    const float inv = (len > 0) ? 1.0f / (float)max(n, 1) : 0.0f;
    float2 r;
    r.x = a0 * inv;
    r.y = a1 * inv;
    *(float2*)(aligned + (size_t)bid * DIN + tid * 2) = r;
}

// ---------------------------------------------------------------------------
// GEMM: h = relu(aligned @ W1 + b1); partial out = h @ W2 -> atomicAdd.
// lane = row (64 rows/block-tile), wave owns 8 h-cols (wave-uniform -> SGPR
// s_load of W1/b1/W2). Grid = 128 row-blocks x 8 col-blocks = 1024, XCD-
// chunked swizzle so the 8 col-siblings share one XCD's L2 for `aligned`.
// LDS: at[KT][64] transposed a-tile; k-loop read at[k][lane] is bank-free.
// ---------------------------------------------------------------------------
__global__ __launch_bounds__(256) void gemm_kernel(
    const float* __restrict__ aligned, const float* __restrict__ W1,
    const float* __restrict__ b1, const float* __restrict__ W2,
    float* __restrict__ acc) {
    __shared__ float at[KT][64];   // 32 KB

    const int raw = blockIdx.x;                       // 0..1023
    const int wid = (raw & 7) * 128 + (raw >> 3);     // XCD-chunked bijection
    const int rowblk = wid >> 3;                      // 0..127
    const int colblk = wid & 7;                       // 0..7
    const int tid  = threadIdx.x;
    const int wave = tid >> 6;
    const int lane = tid & 63;
    const int t0   = rowblk * 64;

    int jw = colblk * 32 + wave * 8;                  // wave's 8 h-cols
    jw = __builtin_amdgcn_readfirstlane(jw);

    // staging mapping: thread = (row sr, k-quarter sq)
    const int sr = tid >> 2;   // 0..63
    const int sq = tid & 3;    // 0..3 -> 32-k chunk

    float a8[8];
    #pragma unroll
    for (int j = 0; j < 8; ++j) a8[j] = 0.0f;

    for (int kt = 0; kt < DIN; kt += KT) {
        const float* src = aligned + (size_t)(t0 + sr) * DIN + kt + sq * 32;
        #pragma unroll
        for (int i = 0; i < 8; ++i) {
            const float4 v = *(const float4*)(src + i * 4);
            const int kk = sq * 32 + i * 4;
            at[kk + 0][sr] = v.x;
            at[kk + 1][sr] = v.y;
            at[kk + 2][sr] = v.z;
            at[kk + 3][sr] = v.w;
        }
        __syncthreads();

        const float* wp = W1 + (size_t)kt * DHID + jw;
        #pragma unroll 4
        for (int k = 0; k < KT; ++k) {
            const float av = at[k][lane];
            #pragma unroll
            for (int j = 0; j < 8; ++j)
                a8[j] = fmaf(av, wp[(size_t)k * DHID + j], a8[j]);
        }
        __syncthreads();
    }

    // layer 2 partial for this wave's 8 cols
    float p0 = 0.f, p1 = 0.f, p2 = 0.f;
    #pragma unroll
    for (int jj = 0; jj < 8; ++jj) {
        const int j = jw + jj;
        const float h = fmaxf(a8[jj] + b1[j], 0.0f);
        p0 = fmaf(h, W2[j * 3 + 0], p0);
        p1 = fmaf(h, W2[j * 3 + 1], p1);
        p2 = fmaf(h, W2[j * 3 + 2], p2);
    }
    const int row = t0 + lane;
    atomicAdd(&acc[row * 3 + 0], p0);
    atomicAdd(&acc[row * 3 + 1], p1);
    atomicAdd(&acc[row * 3 + 2], p2);
}

__global__ __launch_bounds__(256) void epi_kernel(const float* __restrict__ acc,
                                                  const float* __restrict__ b2,
                                                  float* __restrict__ out) {
    const int i = blockIdx.x * 256 + threadIdx.x;
    if (i < NROW * DOUT) out[i] = fmaxf(acc[i] + b2[i % 3], 0.0f);
}

extern "C" void kernel_launch(void* const* d_in, const int* in_sizes, int n_in,
                              void* d_out, int out_size, void* d_ws, size_t ws_size,
                              hipStream_t stream) {
    const float* hs  = (const float*)d_in[0];
    const int*   ds  = (const int*)d_in[1];
    const float* W1  = (const float*)d_in[2];
    const float* b1  = (const float*)d_in[3];
    const float* W2  = (const float*)d_in[4];
    const float* b2  = (const float*)d_in[5];
    const int*   lmx = (const int*)d_in[6];

    float* wsf     = (float*)d_ws;
    int*   starts  = (int*)wsf;
    int*   lens    = starts + NROW;
    float* acc     = wsf + 16384;
    float* aligned = wsf + 65536;

    scan_kernel<<<BB, TMAX, 0, stream>>>(ds, lmx, starts, lens);
    align_kernel<<<NROW, 256, 0, stream>>>(hs, starts, lens, aligned);
    hipMemsetAsync(acc, 0, (size_t)NROW * DOUT * sizeof(float), stream);
    gemm_kernel<<<1024, 256, 0, stream>>>(aligned, W1, b1, W2, acc);
    epi_kernel<<<(NROW * DOUT + 255) / 256, 256, 0, stream>>>(acc, b2,
                                                              (float*)d_out);
}

// Round 3
// 67.950 us; speedup vs baseline: 1.5731x; 1.0971x over previous
//
#include <hip/hip_runtime.h>
#include <math.h>

#define BB    16
#define LL    4096
#define TMAX  512
#define DIN   512
#define DHID  256
#define DOUT  3
#define NROW  (BB * TMAX)   // 8192
#define KT    128           // k-tile for GEMM staging
#define NCB   8             // column blocks (partial buffers)

// ---------------------------------------------------------------------------
// ws layout (float units):
//   [0       .. 8191  ]  starts (int)
//   [8192    .. 16383 ]  lens   (int)
//   [16384   .. 212991]  partials: NCB x (NROW*DOUT) floats
//   [262144  .. +16MB ]  aligned (NROW*DIN floats)
// ---------------------------------------------------------------------------

__global__ __launch_bounds__(TMAX) void scan_kernel(const int* __restrict__ ds,
                                                    const int* __restrict__ lmax,
                                                    int* __restrict__ starts,
                                                    int* __restrict__ lens) {
    __shared__ int sbuf[TMAX];
    const int b = blockIdx.x;
    const int t = threadIdx.x;
    const float mult = (float)LL / (float)lmax[0];
    const int dsv = ds[b * TMAX + t];
    int d = (int)floorf((float)dsv * mult);
    d = max(d, 1);
    const int deff = (dsv > 0) ? d : 0;
    sbuf[t] = deff;
    __syncthreads();
    for (int off = 1; off < TMAX; off <<= 1) {
        int x = (t >= off) ? sbuf[t - off] : 0;
        __syncthreads();
        sbuf[t] += x;
        __syncthreads();
    }
    starts[b * TMAX + t] = sbuf[t] - deff;
    lens[b * TMAX + t]   = deff;
}

// ---------------------------------------------------------------------------
// One block per output row: segment mean (8192 blocks, float2 loads).
// ---------------------------------------------------------------------------
__global__ __launch_bounds__(256) void align_kernel(const float* __restrict__ hs,
                                                    const int* __restrict__ starts,
                                                    const int* __restrict__ lens,
                                                    float* __restrict__ aligned) {
    const int bid = blockIdx.x;          // row id 0..NROW-1
    const int b   = bid >> 9;            // /TMAX
    const int tid = threadIdx.x;

    const int len = lens[bid];
    int s = starts[bid];
    int e = min(s + len, LL);
    s = min(s, LL);
    const int n = e - s;

    const float* p = hs + ((size_t)b * LL + (size_t)s) * DIN + tid * 2;
    float a0 = 0.0f, a1 = 0.0f;
    for (int i = 0; i < n; ++i) {
        const float2 v = *(const float2*)p;
        a0 += v.x;
        a1 += v.y;
        p += DIN;
    }
    const float inv = (len > 0) ? 1.0f / (float)max(n, 1) : 0.0f;
    float2 r;
    r.x = a0 * inv;
    r.y = a1 * inv;
    *(float2*)(aligned + (size_t)bid * DIN + tid * 2) = r;
}

// ---------------------------------------------------------------------------
// GEMM: h = relu(aligned @ W1 + b1); partial out = h @ W2 -> plain store to
// this colblk's partial buffer (no atomics, no memset needed).
// lane = row (64 rows/tile), wave owns 8 h-cols (wave-uniform SGPR loads).
// Grid = 128 row-blocks x 8 col-blocks, XCD-chunked swizzle for L2 reuse
// of `aligned` among the 8 col-siblings.
// ---------------------------------------------------------------------------
__global__ __launch_bounds__(256) void gemm_kernel(
    const float* __restrict__ aligned, const float* __restrict__ W1,
    const float* __restrict__ b1, const float* __restrict__ W2,
    float* __restrict__ partials) {
    __shared__ float at[KT][64];   // 32 KB

    const int raw = blockIdx.x;                       // 0..1023
    const int wid = (raw & 7) * 128 + (raw >> 3);     // XCD-chunked bijection
    const int rowblk = wid >> 3;                      // 0..127
    const int colblk = wid & 7;                       // 0..7
    const int tid  = threadIdx.x;
    const int wave = tid >> 6;
    const int lane = tid & 63;
    const int t0   = rowblk * 64;

    int jw = colblk * 32 + wave * 8;                  // wave's 8 h-cols
    jw = __builtin_amdgcn_readfirstlane(jw);

    const int sr = tid >> 2;   // staging row 0..63
    const int sq = tid & 3;    // staging k-quarter

    float a8[8];
    #pragma unroll
    for (int j = 0; j < 8; ++j) a8[j] = 0.0f;

    for (int kt = 0; kt < DIN; kt += KT) {
        const float* src = aligned + (size_t)(t0 + sr) * DIN + kt + sq * 32;
        #pragma unroll
        for (int i = 0; i < 8; ++i) {
            const float4 v = *(const float4*)(src + i * 4);
            const int kk = sq * 32 + i * 4;
            at[kk + 0][sr] = v.x;
            at[kk + 1][sr] = v.y;
            at[kk + 2][sr] = v.z;
            at[kk + 3][sr] = v.w;
        }
        __syncthreads();

        const float* wp = W1 + (size_t)kt * DHID + jw;
        #pragma unroll 4
        for (int k = 0; k < KT; ++k) {
            const float av = at[k][lane];
            #pragma unroll
            for (int j = 0; j < 8; ++j)
                a8[j] = fmaf(av, wp[(size_t)k * DHID + j], a8[j]);
        }
        __syncthreads();
    }

    // layer 2 partial for this wave's 8 cols -> colblk's buffer
    float p0 = 0.f, p1 = 0.f, p2 = 0.f;
    #pragma unroll
    for (int jj = 0; jj < 8; ++jj) {
        const int j = jw + jj;
        const float h = fmaxf(a8[jj] + b1[j], 0.0f);
        p0 = fmaf(h, W2[j * 3 + 0], p0);
        p1 = fmaf(h, W2[j * 3 + 1], p1);
        p2 = fmaf(h, W2[j * 3 + 2], p2);
    }
    // cross-wave reduce within block (4 waves share the same 64 rows? no --
    // each wave has a different col-group, same rows). Reduce via LDS.
    __shared__ float red[4][64][3];
    red[wave][lane][0] = p0;
    red[wave][lane][1] = p1;
    red[wave][lane][2] = p2;
    __syncthreads();
    if (wave == 0) {
        const int row = t0 + lane;
        float* dst = partials + (size_t)colblk * (NROW * DOUT) + (size_t)row * 3;
        #pragma unroll
        for (int o = 0; o < 3; ++o)
            dst[o] = red[0][lane][o] + red[1][lane][o] + red[2][lane][o] +
                     red[3][lane][o];
    }
}

__global__ __launch_bounds__(256) void epi_kernel(const float* __restrict__ partials,
                                                  const float* __restrict__ b2,
                                                  float* __restrict__ out) {
    const int i = blockIdx.x * 256 + threadIdx.x;
    if (i >= NROW * DOUT) return;
    float a = b2[i % 3];
    #pragma unroll
    for (int c = 0; c < NCB; ++c) a += partials[(size_t)c * (NROW * DOUT) + i];
    out[i] = fmaxf(a, 0.0f);
}

extern "C" void kernel_launch(void* const* d_in, const int* in_sizes, int n_in,
                              void* d_out, int out_size, void* d_ws, size_t ws_size,
                              hipStream_t stream) {
    const float* hs  = (const float*)d_in[0];
    const int*   ds  = (const int*)d_in[1];
    const float* W1  = (const float*)d_in[2];
    const float* b1  = (const float*)d_in[3];
    const float* W2  = (const float*)d_in[4];
    const float* b2  = (const float*)d_in[5];
    const int*   lmx = (const int*)d_in[6];

    float* wsf      = (float*)d_ws;
    int*   starts   = (int*)wsf;
    int*   lens     = starts + NROW;
    float* partials = wsf + 16384;
    float* aligned  = wsf + 262144;

    scan_kernel<<<BB, TMAX, 0, stream>>>(ds, lmx, starts, lens);
    align_kernel<<<NROW, 256, 0, stream>>>(hs, starts, lens, aligned);
    gemm_kernel<<<1024, 256, 0, stream>>>(aligned, W1, b1, W2, partials);
    epi_kernel<<<(NROW * DOUT + 255) / 256, 256, 0, stream>>>(partials, b2,
                                                              (float*)d_out);
}

// Round 4
// 49.717 us; speedup vs baseline: 2.1499x; 1.3667x over previous
//
#include <hip/hip_runtime.h>
#include <math.h>

#define BB    16
#define LL    4096
#define TMAX  512
#define DIN   512
#define DHID  256
#define DOUT  3
#define NROW  (BB * TMAX)   // 8192
#define NCB   8             // column blocks (partial buffers)

typedef __attribute__((ext_vector_type(8))) short bf16x8;   // 8 bf16 = 4 VGPR
typedef __attribute__((ext_vector_type(4))) float f32x4;

static __device__ __forceinline__ ushort f2bf(float x) {
    // round-to-nearest-even fp32 -> bf16
    uint u = __builtin_bit_cast(uint, x);
    u = (u + 0x7FFFu + ((u >> 16) & 1u)) >> 16;
    return (ushort)u;
}

// ---------------------------------------------------------------------------
// ws layout (bytes):
//   [0        .. 32K  )  starts (int[8192])
//   [32K      .. 64K  )  lens   (int[8192])
//   [64K      .. 852K )  partials: NCB x (NROW*DOUT) floats
//   [1M       .. 9.4M )  aligned bf16 [NROW][DIN]  (ushort)
//   [16M      .. 16.25M) W1t bf16 [DHID][DIN]      (ushort)
// ---------------------------------------------------------------------------

__global__ __launch_bounds__(TMAX) void scan_kernel(const int* __restrict__ ds,
                                                    const int* __restrict__ lmax,
                                                    int* __restrict__ starts,
                                                    int* __restrict__ lens) {
    __shared__ int sbuf[TMAX];
    const int b = blockIdx.x;
    const int t = threadIdx.x;
    const float mult = (float)LL / (float)lmax[0];
    const int dsv = ds[b * TMAX + t];
    int d = (int)floorf((float)dsv * mult);
    d = max(d, 1);
    const int deff = (dsv > 0) ? d : 0;
    sbuf[t] = deff;
    __syncthreads();
    for (int off = 1; off < TMAX; off <<= 1) {
        int x = (t >= off) ? sbuf[t - off] : 0;
        __syncthreads();
        sbuf[t] += x;
        __syncthreads();
    }
    starts[b * TMAX + t] = sbuf[t] - deff;
    lens[b * TMAX + t]   = deff;
}

// ---------------------------------------------------------------------------
// W1 [512][256] f32  ->  W1t [256][512] bf16, LDS-tiled 64x64 transpose.
// ---------------------------------------------------------------------------
__global__ __launch_bounds__(256) void wt_kernel(const float* __restrict__ W1,
                                                 ushort* __restrict__ W1t) {
    __shared__ float t[64][65];
    const int bid = blockIdx.x;          // 32 blocks: 8 k-tiles x 4 n-tiles
    const int k0  = (bid >> 2) * 64;
    const int n0  = (bid & 3) * 64;
    const int tid = threadIdx.x;
    const int r   = tid >> 2;            // 0..63
    const int c0  = (tid & 3) * 16;      // 0,16,32,48
    #pragma unroll
    for (int i = 0; i < 4; ++i) {
        const float4 v =
            *(const float4*)&W1[(size_t)(k0 + r) * DHID + n0 + c0 + i * 4];
        t[r][c0 + i * 4 + 0] = v.x;
        t[r][c0 + i * 4 + 1] = v.y;
        t[r][c0 + i * 4 + 2] = v.z;
        t[r][c0 + i * 4 + 3] = v.w;
    }
    __syncthreads();
    #pragma unroll
    for (int i = 0; i < 4; ++i) {
        ushort4 u;
        u.x = f2bf(t[c0 + i * 4 + 0][r]);
        u.y = f2bf(t[c0 + i * 4 + 1][r]);
        u.z = f2bf(t[c0 + i * 4 + 2][r]);
        u.w = f2bf(t[c0 + i * 4 + 3][r]);
        *(ushort4*)&W1t[(size_t)(n0 + r) * DIN + k0 + c0 + i * 4] = u;
    }
}

// ---------------------------------------------------------------------------
// One block per output row: segment mean, bf16 output (8192 blocks).
// ---------------------------------------------------------------------------
__global__ __launch_bounds__(256) void align_kernel(const float* __restrict__ hs,
                                                    const int* __restrict__ starts,
                                                    const int* __restrict__ lens,
                                                    ushort* __restrict__ aligned) {
    const int bid = blockIdx.x;          // row id 0..NROW-1
    const int b   = bid >> 9;            // /TMAX
    const int tid = threadIdx.x;

    const int len = lens[bid];
    int s = starts[bid];
    int e = min(s + len, LL);
    s = min(s, LL);
    const int n = e - s;

    const float* p = hs + ((size_t)b * LL + (size_t)s) * DIN + tid * 2;
    float a0 = 0.0f, a1 = 0.0f;
    for (int i = 0; i < n; ++i) {
        const float2 v = *(const float2*)p;
        a0 += v.x;
        a1 += v.y;
        p += DIN;
    }
    const float inv = (len > 0) ? 1.0f / (float)max(n, 1) : 0.0f;
    ushort2 r2;
    r2.x = f2bf(a0 * inv);
    r2.y = f2bf(a1 * inv);
    *(ushort2*)&aligned[(size_t)bid * DIN + tid * 2] = r2;
}

// ---------------------------------------------------------------------------
// MFMA GEMM: h = relu(A @ W1 + b1); partial = h @ W2 -> per-colblk buffer.
// No LDS: A-frag and B-frag are direct 16B global loads (L2-resident).
// A-frag: lane holds A[row = l&15][k = 8*(l>>4)+j]  (k-contiguous)
// B-frag: lane holds W1t[col = l&15][k = 8*(l>>4)+j] (k-contiguous)
// C/D   : col = l&15, row = (l>>4)*4 + reg           (m89-verified)
// Block = 4 waves, tile 64 rows x 32 cols; grid 128x8, XCD-bijective swizzle.
// ---------------------------------------------------------------------------
__global__ __launch_bounds__(256) void gemm_kernel(
    const ushort* __restrict__ A, const ushort* __restrict__ Bt,
    const float* __restrict__ b1, const float* __restrict__ W2,
    float* __restrict__ partials) {
    const int raw = blockIdx.x;                       // 0..1023
    const int wid = (raw & 7) * 128 + (raw >> 3);     // XCD-chunked bijection
    const int rowblk = wid >> 3;                      // 0..127
    const int colblk = wid & 7;                       // 0..7
    const int tid  = threadIdx.x;
    const int wave = tid >> 6;
    const int lane = tid & 63;
    const int m    = lane & 15;
    const int g    = lane >> 4;
    const int n0   = colblk * 32;

    const ushort* ap  = A  + (size_t)(rowblk * 64 + wave * 16 + m) * DIN + g * 8;
    const ushort* bp0 = Bt + (size_t)(n0 + m) * DIN + g * 8;
    const ushort* bp1 = Bt + (size_t)(n0 + 16 + m) * DIN + g * 8;

    f32x4 acc0 = {0.f, 0.f, 0.f, 0.f};
    f32x4 acc1 = {0.f, 0.f, 0.f, 0.f};
    #pragma unroll 4
    for (int kt = 0; kt < DIN; kt += 32) {
        const bf16x8 av  = *(const bf16x8*)(ap + kt);
        const bf16x8 bv0 = *(const bf16x8*)(bp0 + kt);
        const bf16x8 bv1 = *(const bf16x8*)(bp1 + kt);
        acc0 = __builtin_amdgcn_mfma_f32_16x16x32_bf16(av, bv0, acc0, 0, 0, 0);
        acc1 = __builtin_amdgcn_mfma_f32_16x16x32_bf16(av, bv1, acc1, 0, 0, 0);
    }

    // ---- fused layer 2: h = relu(acc + b1); p += h * W2 ----
    float p[4][3] = {{0.f, 0.f, 0.f}, {0.f, 0.f, 0.f},
                     {0.f, 0.f, 0.f}, {0.f, 0.f, 0.f}};
    {   // fragment f = 0, cols n0 + m
        const int col = n0 + m;
        const float bb = b1[col];
        const float w0 = W2[col * 3 + 0];
        const float w1 = W2[col * 3 + 1];
        const float w2 = W2[col * 3 + 2];
        #pragma unroll
        for (int r = 0; r < 4; ++r) {
            const float h = fmaxf(acc0[r] + bb, 0.0f);
            p[r][0] = fmaf(h, w0, p[r][0]);
            p[r][1] = fmaf(h, w1, p[r][1]);
            p[r][2] = fmaf(h, w2, p[r][2]);
        }
    }
    {   // fragment f = 1, cols n0 + 16 + m
        const int col = n0 + 16 + m;
        const float bb = b1[col];
        const float w0 = W2[col * 3 + 0];
        const float w1 = W2[col * 3 + 1];
        const float w2 = W2[col * 3 + 2];
        #pragma unroll
        for (int r = 0; r < 4; ++r) {
            const float h = fmaxf(acc1[r] + bb, 0.0f);
            p[r][0] = fmaf(h, w0, p[r][0]);
            p[r][1] = fmaf(h, w1, p[r][1]);
            p[r][2] = fmaf(h, w2, p[r][2]);
        }
    }
    // reduce over the 16 lanes (col index m) within each l>>4 group
    #pragma unroll
    for (int mask = 1; mask < 16; mask <<= 1)
        #pragma unroll
        for (int r = 0; r < 4; ++r)
            #pragma unroll
            for (int o = 0; o < 3; ++o)
                p[r][o] += __shfl_xor(p[r][o], mask, 64);

    if (m == 0) {
        const int rowb = rowblk * 64 + wave * 16 + g * 4;   // 4 rows: rowb..+3
        float* dst = partials + (size_t)colblk * (NROW * DOUT) + (size_t)rowb * 3;
        #pragma unroll
        for (int r = 0; r < 4; ++r)
            #pragma unroll
            for (int o = 0; o < 3; ++o)
                dst[r * 3 + o] = p[r][o];
    }
}

__global__ __launch_bounds__(256) void epi_kernel(const float* __restrict__ partials,
                                                  const float* __restrict__ b2,
                                                  float* __restrict__ out) {
    const int i = blockIdx.x * 256 + threadIdx.x;
    if (i >= NROW * DOUT) return;
    float a = b2[i % 3];
    #pragma unroll
    for (int c = 0; c < NCB; ++c) a += partials[(size_t)c * (NROW * DOUT) + i];
    out[i] = fmaxf(a, 0.0f);
}

extern "C" void kernel_launch(void* const* d_in, const int* in_sizes, int n_in,
                              void* d_out, int out_size, void* d_ws, size_t ws_size,
                              hipStream_t stream) {
    const float* hs  = (const float*)d_in[0];
    const int*   ds  = (const int*)d_in[1];
    const float* W1  = (const float*)d_in[2];
    const float* b1  = (const float*)d_in[3];
    const float* W2  = (const float*)d_in[4];
    const float* b2  = (const float*)d_in[5];
    const int*   lmx = (const int*)d_in[6];

    char*   wsb      = (char*)d_ws;
    int*    starts   = (int*)wsb;
    int*    lens     = (int*)(wsb + 32 * 1024);
    float*  partials = (float*)(wsb + 64 * 1024);
    ushort* aligned  = (ushort*)(wsb + (1 << 20));
    ushort* W1t      = (ushort*)(wsb + (16 << 20));

    scan_kernel<<<BB, TMAX, 0, stream>>>(ds, lmx, starts, lens);
    wt_kernel<<<32, 256, 0, stream>>>(W1, W1t);
    align_kernel<<<NROW, 256, 0, stream>>>(hs, starts, lens, aligned);
    gemm_kernel<<<1024, 256, 0, stream>>>(aligned, W1t, b1, W2, partials);
    epi_kernel<<<(NROW * DOUT + 255) / 256, 256, 0, stream>>>(partials, b2,
                                                              (float*)d_out);
}

// Round 6
// 48.652 us; speedup vs baseline: 2.1970x; 1.0219x over previous
//
#include <hip/hip_runtime.h>
#include <math.h>

#define BB    16
#define LL    4096
#define TMAX  512
#define DIN   512
#define DHID  256
#define DOUT  3
#define NROW  (BB * TMAX)   // 8192
#define RPB   16            // rows per fused block

typedef __attribute__((ext_vector_type(8))) short bf16x8;   // 8 bf16 = 4 VGPR
typedef __attribute__((ext_vector_type(4))) float f32x4;

static __device__ __forceinline__ ushort f2bf(float x) {
    uint u = __builtin_bit_cast(uint, x);
    u = (u + 0x7FFFu + ((u >> 16) & 1u)) >> 16;
    return (ushort)u;
}

// ---------------------------------------------------------------------------
// ws layout (bytes):
//   [0    .. 32K )  starts (int[8192])
//   [32K  .. 64K )  lens   (int[8192])
//   [64K  .. 320K)  W1t bf16 [DHID][DIN] (ushort)
// ---------------------------------------------------------------------------

// ---------------------------------------------------------------------------
// Prep: blocks 0..15 = per-batch duration scan; blocks 16..47 = W1 transpose
// to bf16 [256][512] (64x64 tiles).
// ---------------------------------------------------------------------------
__global__ __launch_bounds__(512) void prep_kernel(
    const int* __restrict__ ds, const int* __restrict__ lmax,
    const float* __restrict__ W1, int* __restrict__ starts,
    int* __restrict__ lens, ushort* __restrict__ W1t) {
    __shared__ int   sbuf[TMAX];
    __shared__ float t[64][65];
    const int bid = blockIdx.x;
    const int tid = threadIdx.x;

    if (bid < BB) {                       // ---- scan ----
        const int b = bid;
        const float mult = (float)LL / (float)lmax[0];
        const int dsv = ds[b * TMAX + tid];
        int d = (int)floorf((float)dsv * mult);
        d = max(d, 1);
        const int deff = (dsv > 0) ? d : 0;
        sbuf[tid] = deff;
        __syncthreads();
        for (int off = 1; off < TMAX; off <<= 1) {
            int x = (tid >= off) ? sbuf[tid - off] : 0;
            __syncthreads();
            sbuf[tid] += x;
            __syncthreads();
        }
        starts[b * TMAX + tid] = sbuf[tid] - deff;
        lens[b * TMAX + tid]   = deff;
    } else {                              // ---- W1 transpose ----
        const int tb = bid - BB;          // 0..31: 8 k-tiles x 4 n-tiles
        const int k0 = (tb >> 2) * 64;
        const int n0 = (tb & 3) * 64;
        const int r  = tid >> 3;          // 0..63
        const int c8 = (tid & 7) * 8;     // 0..56
        #pragma unroll
        for (int i = 0; i < 2; ++i) {
            const float4 v =
                *(const float4*)&W1[(size_t)(k0 + r) * DHID + n0 + c8 + i * 4];
            t[r][c8 + i * 4 + 0] = v.x;
            t[r][c8 + i * 4 + 1] = v.y;
            t[r][c8 + i * 4 + 2] = v.z;
            t[r][c8 + i * 4 + 3] = v.w;
        }
        __syncthreads();
        #pragma unroll
        for (int i = 0; i < 2; ++i) {
            ushort4 u;
            u.x = f2bf(t[c8 + i * 4 + 0][r]);
            u.y = f2bf(t[c8 + i * 4 + 1][r]);
            u.z = f2bf(t[c8 + i * 4 + 2][r]);
            u.w = f2bf(t[c8 + i * 4 + 3][r]);
            *(ushort4*)&W1t[(size_t)(n0 + r) * DIN + k0 + c8 + i * 4] = u;
        }
    }
}

// ---------------------------------------------------------------------------
// Fused: segment-mean (16 rows -> swizzled LDS bf16 A-tile) + MFMA GEMM
// (16x256, K=512, B = W1t direct from L2) + fused layer-2 -> d_out.
// Phase 1: ALL 256 threads per row (thread owns cols tid*2, tid*2+1),
//          looping the block's 16 rows -- full 512-column coverage.
//          LDS write at byte tid*4 ^ ((row&7)<<4)  (same involution as read).
// Phase 2: wave w owns cols w*64..w*64+63 (4 x 16x16x32 MFMA frags).
//   A-frag: lane holds A[row=l&15][k=8*(l>>4)+j] via swizzled 16B LDS read
//   B-frag: lane holds W1t[col][k] 16B global load (L2-resident)
//   C/D:    col = l&15, row = (l>>4)*4 + reg
// Grid = 512 blocks, XCD-chunked bijection (512 = 8 x 64).
// ---------------------------------------------------------------------------
__global__ __launch_bounds__(256, 2) void fused_kernel(
    const float* __restrict__ hs, const int* __restrict__ starts,
    const int* __restrict__ lens, const ushort* __restrict__ W1t,
    const float* __restrict__ b1, const float* __restrict__ W2,
    const float* __restrict__ b2, float* __restrict__ out) {
    __shared__ ushort Asw[RPB * DIN];        // 16KB, XOR-swizzled rows
    __shared__ float  red[4][RPB][DOUT];     // 768B

    const int raw  = blockIdx.x;             // 0..511
    const int bid  = (raw & 7) * 64 + (raw >> 3);   // XCD-chunked bijection
    const int row0 = bid * RPB;
    const int b    = row0 >> 9;              // batch (512 rows per batch)
    const int tid  = threadIdx.x;
    const int w    = tid >> 6;               // wave 0..3
    const int l    = tid & 63;
    const int m    = l & 15;
    const int g    = l >> 4;

    // ---- phase 1: segment means, whole block per row, 16 rows ----
    #pragma unroll 2
    for (int rl = 0; rl < RPB; ++rl) {
        const int row = row0 + rl;
        const int len = lens[row];
        int s = starts[row];
        int e = min(s + len, LL);
        s = min(s, LL);
        const int n = e - s;
        const float* p = hs + ((size_t)b * LL + (size_t)s) * DIN + tid * 2;
        float a0 = 0.0f, a1 = 0.0f;
        for (int i = 0; i < n; ++i) {
            const float2 v = *(const float2*)p;
            a0 += v.x;
            a1 += v.y;
            p += DIN;
        }
        const float inv = (len > 0) ? 1.0f / (float)max(n, 1) : 0.0f;
        ushort2 u;
        u.x = f2bf(a0 * inv);
        u.y = f2bf(a1 * inv);
        *(ushort2*)((char*)Asw + rl * 1024 + ((tid * 4) ^ ((rl & 7) << 4))) = u;
    }
    __syncthreads();

    // ---- phase 2: GEMM 16 x 64 (this wave) over K = 512 ----
    f32x4 acc[4] = {{0.f, 0.f, 0.f, 0.f}, {0.f, 0.f, 0.f, 0.f},
                    {0.f, 0.f, 0.f, 0.f}, {0.f, 0.f, 0.f, 0.f}};
    const ushort* bp[4];
    #pragma unroll
    for (int fc = 0; fc < 4; ++fc)
        bp[fc] = W1t + (size_t)(w * 64 + fc * 16 + m) * DIN + g * 8;

    const char* abase = (const char*)Asw + m * 1024;
    const int   aswz  = (m & 7) << 4;
    #pragma unroll 4
    for (int kt = 0; kt < DIN; kt += 32) {
        const bf16x8 av = *(const bf16x8*)(abase + ((g * 16 + kt * 2) ^ aswz));
        #pragma unroll
        for (int fc = 0; fc < 4; ++fc) {
            const bf16x8 bv = *(const bf16x8*)(bp[fc] + kt);
            acc[fc] = __builtin_amdgcn_mfma_f32_16x16x32_bf16(av, bv, acc[fc],
                                                              0, 0, 0);
        }
    }

    // ---- phase 3: layer 2 (h = relu(acc+b1); p += h*W2), reduce, store ----
    float p[4][3] = {{0.f, 0.f, 0.f}, {0.f, 0.f, 0.f},
                     {0.f, 0.f, 0.f}, {0.f, 0.f, 0.f}};
    #pragma unroll
    for (int fc = 0; fc < 4; ++fc) {
        const int col = w * 64 + fc * 16 + m;
        const float bb = b1[col];
        const float w20 = W2[col * 3 + 0];
        const float w21 = W2[col * 3 + 1];
        const float w22 = W2[col * 3 + 2];
        #pragma unroll
        for (int r = 0; r < 4; ++r) {
            const float h = fmaxf(acc[fc][r] + bb, 0.0f);
            p[r][0] = fmaf(h, w20, p[r][0]);
            p[r][1] = fmaf(h, w21, p[r][1]);
            p[r][2] = fmaf(h, w22, p[r][2]);
        }
    }
    #pragma unroll
    for (int mask = 1; mask < 16; mask <<= 1)
        #pragma unroll
        for (int r = 0; r < 4; ++r)
            #pragma unroll
            for (int o = 0; o < 3; ++o)
                p[r][o] += __shfl_xor(p[r][o], mask, 64);

    if (m == 0) {
        #pragma unroll
        for (int r = 0; r < 4; ++r)
            #pragma unroll
            for (int o = 0; o < 3; ++o)
                red[w][g * 4 + r][o] = p[r][o];
    }
    __syncthreads();

    if (tid < RPB * DOUT) {
        const int rl = tid / 3;
        const int o  = tid % 3;
        const float v = red[0][rl][o] + red[1][rl][o] + red[2][rl][o] +
                        red[3][rl][o] + b2[o];
        out[(size_t)(row0 + rl) * DOUT + o] = fmaxf(v, 0.0f);
    }
}

extern "C" void kernel_launch(void* const* d_in, const int* in_sizes, int n_in,
                              void* d_out, int out_size, void* d_ws, size_t ws_size,
                              hipStream_t stream) {
    const float* hs  = (const float*)d_in[0];
    const int*   ds  = (const int*)d_in[1];
    const float* W1  = (const float*)d_in[2];
    const float* b1  = (const float*)d_in[3];
    const float* W2  = (const float*)d_in[4];
    const float* b2  = (const float*)d_in[5];
    const int*   lmx = (const int*)d_in[6];

    char*   wsb    = (char*)d_ws;
    int*    starts = (int*)wsb;
    int*    lens   = (int*)(wsb + 32 * 1024);
    ushort* W1t    = (ushort*)(wsb + 64 * 1024);

    prep_kernel<<<BB + 32, 512, 0, stream>>>(ds, lmx, W1, starts, lens, W1t);
    fused_kernel<<<NROW / RPB, 256, 0, stream>>>(hs, starts, lens, W1t, b1, W2,
                                                 b2, (float*)d_out);
}